// Round 4
// baseline (8370.003 us; speedup 1.0000x reference)
//
#include <hip/hip_runtime.h>

constexpr int NN = 150000;   // nodes
constexpr int NE = 4800000;  // edges
constexpr int NG = 512;      // graphs
constexpr int H  = 16;       // hidden

// ---------------- degree ----------------
__global__ void k_deg_init(float* __restrict__ deg) {
    int i = blockIdx.x * blockDim.x + threadIdx.x;
    if (i < NN) deg[i] = 1.0f;  // self-loop
}

__global__ void k_deg_edges(const int* __restrict__ dst, float* __restrict__ deg) {
    int i = blockIdx.x * blockDim.x + threadIdx.x;
    if (i < NE) atomicAdd(&deg[dst[i]], 1.0f);
}

__global__ void k_disq(float* __restrict__ deg) {
    int i = blockIdx.x * blockDim.x + threadIdx.x;
    if (i < NN) deg[i] = rsqrtf(deg[i]);  // deg >= 1 always
}

// ---------------- conv1: y = (x @ W1) * disq ; acc = y (self-loop term) ----------------
__global__ void k_xw1(const float* __restrict__ x, const float* __restrict__ W1,
                      const float* __restrict__ disq,
                      float* __restrict__ y, float* __restrict__ acc) {
    __shared__ float w[4 * H];
    if (threadIdx.x < 4 * H) w[threadIdx.x] = W1[threadIdx.x];
    __syncthreads();
    int i = blockIdx.x * blockDim.x + threadIdx.x;
    if (i >= NN) return;
    float4 xv = ((const float4*)x)[i];
    float d = disq[i];
    float o[H];
#pragma unroll
    for (int h = 0; h < H; ++h)
        o[h] = (xv.x * w[0*H + h] + xv.y * w[1*H + h] +
                xv.z * w[2*H + h] + xv.w * w[3*H + h]) * d;
    float4* yp = (float4*)(y   + (size_t)i * H);
    float4* ap = (float4*)(acc + (size_t)i * H);
#pragma unroll
    for (int q = 0; q < 4; ++q) { yp[q] = ((float4*)o)[q]; ap[q] = ((float4*)o)[q]; }
}

// ---------------- edge scatter: acc[dst] += y[src] ----------------
__global__ void k_scatter(const int* __restrict__ src, const int* __restrict__ dst,
                          const float* __restrict__ y, float* __restrict__ acc) {
    int i = blockIdx.x * blockDim.x + threadIdx.x;
    if (i >= NE) return;
    int s = src[i], d = dst[i];
    const float4* yp = (const float4*)(y + (size_t)s * H);
    float* ap = acc + (size_t)d * H;
#pragma unroll
    for (int q = 0; q < 4; ++q) {
        float4 v = yp[q];
        atomicAdd(ap + q*4 + 0, v.x);
        atomicAdd(ap + q*4 + 1, v.y);
        atomicAdd(ap + q*4 + 2, v.z);
        atomicAdd(ap + q*4 + 3, v.w);
    }
}

// ---------------- post: h = relu(acc * disq + b) ----------------
__global__ void k_post(const float* __restrict__ acc, const float* __restrict__ disq,
                       const float* __restrict__ b, float* __restrict__ hout) {
    __shared__ float bs[H];
    if (threadIdx.x < H) bs[threadIdx.x] = b[threadIdx.x];
    __syncthreads();
    int i = blockIdx.x * blockDim.x + threadIdx.x;
    if (i >= NN) return;
    float d = disq[i];
    const float4* ap = (const float4*)(acc + (size_t)i * H);
    float4* hp = (float4*)(hout + (size_t)i * H);
#pragma unroll
    for (int q = 0; q < 4; ++q) {
        float4 v = ap[q];
        float4 r;
        r.x = fmaxf(v.x * d + bs[q*4+0], 0.f);
        r.y = fmaxf(v.y * d + bs[q*4+1], 0.f);
        r.z = fmaxf(v.z * d + bs[q*4+2], 0.f);
        r.w = fmaxf(v.w * d + bs[q*4+3], 0.f);
        hp[q] = r;
    }
}

// ---------------- conv2 pre: y = (h @ W2) * disq -> yout; acc init -> overwrite h buffer ----------------
__global__ void k_hw2(float* __restrict__ hin_acc, const float* __restrict__ W2,
                      const float* __restrict__ disq, float* __restrict__ yout) {
    __shared__ float w[H * H];
    if (threadIdx.x < H * H) w[threadIdx.x] = W2[threadIdx.x];
    __syncthreads();
    int i = blockIdx.x * blockDim.x + threadIdx.x;
    if (i >= NN) return;
    float hv[H];
    const float4* hp = (const float4*)(hin_acc + (size_t)i * H);
#pragma unroll
    for (int q = 0; q < 4; ++q) ((float4*)hv)[q] = hp[q];
    float d = disq[i];
    float o[H];
#pragma unroll
    for (int h = 0; h < H; ++h) {
        float s = 0.f;
#pragma unroll
        for (int k = 0; k < H; ++k) s += hv[k] * w[k*H + h];
        o[h] = s * d;
    }
    float4* yp = (float4*)(yout    + (size_t)i * H);
    float4* ap = (float4*)(hin_acc + (size_t)i * H);
#pragma unroll
    for (int q = 0; q < 4; ++q) { yp[q] = ((float4*)o)[q]; ap[q] = ((float4*)o)[q]; }
}

// ---------------- pool: g[batch[i]] += h[i] ----------------
__global__ void k_pool(const float* __restrict__ h, const int* __restrict__ batch,
                       float* __restrict__ g) {
    int i = blockIdx.x * blockDim.x + threadIdx.x;
    if (i >= NN) return;
    int b = batch[i];
    const float4* hp = (const float4*)(h + (size_t)i * H);
    float* gp = g + (size_t)b * H;
#pragma unroll
    for (int q = 0; q < 4; ++q) {
        float4 v = hp[q];
        atomicAdd(gp + q*4 + 0, v.x);
        atomicAdd(gp + q*4 + 1, v.y);
        atomicAdd(gp + q*4 + 2, v.z);
        atomicAdd(gp + q*4 + 3, v.w);
    }
}

// ---------------- final MLP: out = relu(g@Wf1+bf1) @ Wf2 + bf2 ----------------
__global__ void k_mlp(const float* __restrict__ g, const float* __restrict__ Wf1,
                      const float* __restrict__ bf1, const float* __restrict__ Wf2,
                      const float* __restrict__ bf2, float* __restrict__ out) {
    __shared__ float w1[H * H];
    __shared__ float b1s[H];
    __shared__ float w2[H];
    __shared__ float b2s;
    if (threadIdx.x < H * H) w1[threadIdx.x] = Wf1[threadIdx.x];
    if (threadIdx.x < H) { b1s[threadIdx.x] = bf1[threadIdx.x]; w2[threadIdx.x] = Wf2[threadIdx.x]; }
    if (threadIdx.x == 0) b2s = bf2[0];
    __syncthreads();
    int i = blockIdx.x * blockDim.x + threadIdx.x;
    if (i >= NG) return;
    float gv[H];
    const float4* gp = (const float4*)(g + (size_t)i * H);
#pragma unroll
    for (int q = 0; q < 4; ++q) ((float4*)gv)[q] = gp[q];
    float s2 = 0.f;
#pragma unroll
    for (int h = 0; h < H; ++h) {
        float t = b1s[h];
#pragma unroll
        for (int k = 0; k < H; ++k) t += gv[k] * w1[k*H + h];
        s2 += fmaxf(t, 0.f) * w2[h];
    }
    out[i] = s2 + b2s;
}

extern "C" void kernel_launch(void* const* d_in, const int* in_sizes, int n_in,
                              void* d_out, int out_size, void* d_ws, size_t ws_size,
                              hipStream_t stream) {
    const float* x   = (const float*)d_in[0];
    const float* W1  = (const float*)d_in[1];
    const float* b1  = (const float*)d_in[2];
    const float* W2  = (const float*)d_in[3];
    const float* b2  = (const float*)d_in[4];
    const float* Wf1 = (const float*)d_in[5];
    const float* bf1 = (const float*)d_in[6];
    const float* Wf2 = (const float*)d_in[7];
    const float* bf2 = (const float*)d_in[8];
    const int*   ei    = (const int*)d_in[9];
    const int*   batch = (const int*)d_in[10];
    const int* src = ei;        // edge_index row 0
    const int* dst = ei + NE;   // edge_index row 1
    float* out = (float*)d_out;

    float* ws   = (float*)d_ws;
    float* deg  = ws;                         // NN floats (deg, then disq in-place)
    float* bufA = ws + NN;                    // NN*H
    float* bufB = bufA + (size_t)NN * H;      // NN*H
    float* g    = bufB + (size_t)NN * H;      // NG*H

    const int BT = 256;
    const int gbN = (NN + BT - 1) / BT;
    const int gbE = (NE + BT - 1) / BT;

    // degree -> disq
    k_deg_init<<<gbN, BT, 0, stream>>>(deg);
    k_deg_edges<<<gbE, BT, 0, stream>>>(dst, deg);
    k_disq<<<gbN, BT, 0, stream>>>(deg);

    // conv1: y1 = A, acc1 = B
    k_xw1<<<gbN, BT, 0, stream>>>(x, W1, deg, bufA, bufB);
    k_scatter<<<gbE, BT, 0, stream>>>(src, dst, bufA, bufB);
    k_post<<<gbN, BT, 0, stream>>>(bufB, deg, b1, bufA);      // h1 -> A

    // conv2: y2 = B, acc2 = A (init inside k_hw2)
    k_hw2<<<gbN, BT, 0, stream>>>(bufA, W2, deg, bufB);
    k_scatter<<<gbE, BT, 0, stream>>>(src, dst, bufB, bufA);
    k_post<<<gbN, BT, 0, stream>>>(bufA, deg, b2, bufB);      // h2 -> B

    // pool + MLP
    hipMemsetAsync(g, 0, (size_t)NG * H * sizeof(float), stream);
    k_pool<<<gbN, BT, 0, stream>>>(bufB, batch, g);
    k_mlp<<<1, 512, 0, stream>>>(g, Wf1, bf1, Wf2, bf2, out);
}

// Round 6
// 923.965 us; speedup vs baseline: 9.0588x; 9.0588x over previous
//
#include <hip/hip_runtime.h>

constexpr int NN = 150000;   // nodes
constexpr int NE = 4800000;  // edges
constexpr int NG = 512;      // graphs
constexpr int H  = 16;       // hidden
constexpr int SCAN_BS = 256;
constexpr int NB1 = (NN + SCAN_BS - 1) / SCAN_BS;   // 586 scan blocks

// ================= CSR build (counting sort by dst) =================
__global__ void k_count(const int* __restrict__ dst, int* __restrict__ cnt) {
    int i = blockIdx.x * blockDim.x + threadIdx.x;
    if (i < NE) atomicAdd(&cnt[dst[i]], 1);
}

// exclusive scan of cnt -> partial (stored into rs), block sums -> bsum
__global__ void k_scan1(const int* __restrict__ cnt, int* __restrict__ partial,
                        int* __restrict__ bsum) {
    __shared__ int tmp[SCAN_BS];
    int t = threadIdx.x;
    int i = blockIdx.x * SCAN_BS + t;
    int v = (i < NN) ? cnt[i] : 0;
    tmp[t] = v;
    __syncthreads();
    for (int off = 1; off < SCAN_BS; off <<= 1) {
        int add = (t >= off) ? tmp[t - off] : 0;
        __syncthreads();
        tmp[t] += add;
        __syncthreads();
    }
    if (i < NN) partial[i] = tmp[t] - v;            // exclusive
    if (t == SCAN_BS - 1) bsum[blockIdx.x] = tmp[t];
}

__global__ void k_scan2(const int* __restrict__ bsum, int* __restrict__ bscan) {
    __shared__ int tmp[1024];
    int t = threadIdx.x;
    int v = (t < NB1) ? bsum[t] : 0;
    tmp[t] = v;
    __syncthreads();
    for (int off = 1; off < 1024; off <<= 1) {
        int add = (t >= off) ? tmp[t - off] : 0;
        __syncthreads();
        tmp[t] += add;
        __syncthreads();
    }
    bscan[t] = tmp[t] - v;                          // exclusive
}

// finalize row_start + cursor copy + disq = rsqrt(deg) (deg = cnt+1 self-loop)
__global__ void k_scan3(const int* __restrict__ cnt, const int* __restrict__ bscan,
                        int* __restrict__ rs, int* __restrict__ cursor,
                        float* __restrict__ disq) {
    int i = blockIdx.x * blockDim.x + threadIdx.x;
    if (i < NN) {
        int r = rs[i] + bscan[i >> 8];              // rs held block-local partial
        rs[i] = r;
        cursor[i] = r;
        disq[i] = rsqrtf((float)(cnt[i] + 1));
    }
    if (i == 0) rs[NN] = NE;
}

__global__ void k_place(const int* __restrict__ src, const int* __restrict__ dst,
                        int* __restrict__ cursor, int* __restrict__ csr) {
    int i = blockIdx.x * blockDim.x + threadIdx.x;
    if (i < NE) {
        int p = atomicAdd(&cursor[dst[i]], 1);
        csr[p] = src[i];
    }
}

// ================= dense node-local kernels =================
// y = (x @ W1) * disq   (x is [N,4])
__global__ void k_xw1(const float* __restrict__ x, const float* __restrict__ W1,
                      const float* __restrict__ disq, float* __restrict__ y) {
    __shared__ float w[4 * H];
    if (threadIdx.x < 4 * H) w[threadIdx.x] = W1[threadIdx.x];
    __syncthreads();
    int i = blockIdx.x * blockDim.x + threadIdx.x;
    if (i >= NN) return;
    float4 xv = ((const float4*)x)[i];
    float d = disq[i];
    float o[H];
#pragma unroll
    for (int h = 0; h < H; ++h)
        o[h] = (xv.x * w[0*H + h] + xv.y * w[1*H + h] +
                xv.z * w[2*H + h] + xv.w * w[3*H + h]) * d;
    float4* yp = (float4*)(y + (size_t)i * H);
#pragma unroll
    for (int q = 0; q < 4; ++q) yp[q] = ((float4*)o)[q];
}

// y = (h @ W2) * disq
__global__ void k_hw2(const float* __restrict__ hin, const float* __restrict__ W2,
                      const float* __restrict__ disq, float* __restrict__ yout) {
    __shared__ float w[H * H];
    if (threadIdx.x < H * H) w[threadIdx.x] = W2[threadIdx.x];
    __syncthreads();
    int i = blockIdx.x * blockDim.x + threadIdx.x;
    if (i >= NN) return;
    float hv[H];
    const float4* hp = (const float4*)(hin + (size_t)i * H);
#pragma unroll
    for (int q = 0; q < 4; ++q) ((float4*)hv)[q] = hp[q];
    float d = disq[i];
    float o[H];
#pragma unroll
    for (int h = 0; h < H; ++h) {
        float s = 0.f;
#pragma unroll
        for (int k = 0; k < H; ++k) s += hv[k] * w[k*H + h];
        o[h] = s * d;
    }
    float4* yp = (float4*)(yout + (size_t)i * H);
#pragma unroll
    for (int q = 0; q < 4; ++q) yp[q] = ((float4*)o)[q];
}

// ============ gather aggregation: h[n] = relu(disq[n]*(y[n] + sum y[csr]) + b) ============
// 16 lanes per node: lane j owns feature j -> coalesced 64B row loads, no atomics.
__global__ void k_gather(const int* __restrict__ rs, const int* __restrict__ csr,
                         const float* __restrict__ y, const float* __restrict__ disq,
                         const float* __restrict__ b, float* __restrict__ hout) {
    int n    = blockIdx.x * (blockDim.x / H) + threadIdx.x / H;
    int lane = threadIdx.x & (H - 1);
    if (n >= NN) return;
    int s0 = rs[n], s1 = rs[n + 1];
    float acc = y[(size_t)n * H + lane];            // self-loop term
    int k = s0;
    for (; k + 1 < s1; k += 2) {                    // 2-way ILP
        int sa = csr[k], sb = csr[k + 1];
        float va = y[(size_t)sa * H + lane];
        float vb = y[(size_t)sb * H + lane];
        acc += va; acc += vb;
    }
    if (k < s1) acc += y[(size_t)csr[k] * H + lane];
    hout[(size_t)n * H + lane] = fmaxf(fmaf(acc, disq[n], b[lane]), 0.f);
}

// ============ pool: batch is sorted -> binary-search segmented sum, no atomics ============
__global__ void k_pool_seg(const float* __restrict__ h, const int* __restrict__ batch,
                           float* __restrict__ gout) {
    int g    = blockIdx.x * (blockDim.x / H) + threadIdx.x / H;
    int lane = threadIdx.x & (H - 1);
    if (g >= NG) return;
    int lo = 0, hi = NN;
    while (lo < hi) { int m = (lo + hi) >> 1; if (batch[m] < g) lo = m + 1; else hi = m; }
    int start = lo;
    hi = NN;
    while (lo < hi) { int m = (lo + hi) >> 1; if (batch[m] < g + 1) lo = m + 1; else hi = m; }
    int end = lo;
    float acc = 0.f;
    for (int i = start; i < end; ++i) acc += h[(size_t)i * H + lane];
    gout[(size_t)g * H + lane] = acc;
}

// ================= final MLP =================
__global__ void k_mlp(const float* __restrict__ g, const float* __restrict__ Wf1,
                      const float* __restrict__ bf1, const float* __restrict__ Wf2,
                      const float* __restrict__ bf2, float* __restrict__ out) {
    __shared__ float w1[H * H];
    __shared__ float b1s[H];
    __shared__ float w2[H];
    __shared__ float b2s;
    if (threadIdx.x < H * H) w1[threadIdx.x] = Wf1[threadIdx.x];
    if (threadIdx.x < H) { b1s[threadIdx.x] = bf1[threadIdx.x]; w2[threadIdx.x] = Wf2[threadIdx.x]; }
    if (threadIdx.x == 0) b2s = bf2[0];
    __syncthreads();
    int i = blockIdx.x * blockDim.x + threadIdx.x;
    if (i >= NG) return;
    float gv[H];
    const float4* gp = (const float4*)(g + (size_t)i * H);
#pragma unroll
    for (int q = 0; q < 4; ++q) ((float4*)gv)[q] = gp[q];
    float s2 = 0.f;
#pragma unroll
    for (int h = 0; h < H; ++h) {
        float t = b1s[h];
#pragma unroll
        for (int k = 0; k < H; ++k) t += gv[k] * w1[k*H + h];
        s2 += fmaxf(t, 0.f) * w2[h];
    }
    out[i] = s2 + b2s;
}

// ================= fallback (baseline atomic path) =================
__global__ void k_deg_init(float* __restrict__ deg) {
    int i = blockIdx.x * blockDim.x + threadIdx.x;
    if (i < NN) deg[i] = 1.0f;
}
__global__ void k_deg_edges(const int* __restrict__ dst, float* __restrict__ deg) {
    int i = blockIdx.x * blockDim.x + threadIdx.x;
    if (i < NE) atomicAdd(&deg[dst[i]], 1.0f);
}
__global__ void k_disq(float* __restrict__ deg) {
    int i = blockIdx.x * blockDim.x + threadIdx.x;
    if (i < NN) deg[i] = rsqrtf(deg[i]);
}
__global__ void k_scatter(const int* __restrict__ src, const int* __restrict__ dst,
                          const float* __restrict__ y, float* __restrict__ acc) {
    int i = blockIdx.x * blockDim.x + threadIdx.x;
    if (i >= NE) return;
    int s = src[i], d = dst[i];
    const float4* yp = (const float4*)(y + (size_t)s * H);
    float* ap = acc + (size_t)d * H;
#pragma unroll
    for (int q = 0; q < 4; ++q) {
        float4 v = yp[q];
        atomicAdd(ap + q*4 + 0, v.x);
        atomicAdd(ap + q*4 + 1, v.y);
        atomicAdd(ap + q*4 + 2, v.z);
        atomicAdd(ap + q*4 + 3, v.w);
    }
}
__global__ void k_post(const float* __restrict__ acc, const float* __restrict__ disq,
                       const float* __restrict__ b, float* __restrict__ hout) {
    __shared__ float bs[H];
    if (threadIdx.x < H) bs[threadIdx.x] = b[threadIdx.x];
    __syncthreads();
    int i = blockIdx.x * blockDim.x + threadIdx.x;
    if (i >= NN) return;
    float d = disq[i];
    const float4* ap = (const float4*)(acc + (size_t)i * H);
    float4* hp = (float4*)(hout + (size_t)i * H);
#pragma unroll
    for (int q = 0; q < 4; ++q) {
        float4 v = ap[q];
        float4 r;
        r.x = fmaxf(v.x * d + bs[q*4+0], 0.f);
        r.y = fmaxf(v.y * d + bs[q*4+1], 0.f);
        r.z = fmaxf(v.z * d + bs[q*4+2], 0.f);
        r.w = fmaxf(v.w * d + bs[q*4+3], 0.f);
        hp[q] = r;
    }
}

extern "C" void kernel_launch(void* const* d_in, const int* in_sizes, int n_in,
                              void* d_out, int out_size, void* d_ws, size_t ws_size,
                              hipStream_t stream) {
    const float* x   = (const float*)d_in[0];
    const float* W1  = (const float*)d_in[1];
    const float* b1  = (const float*)d_in[2];
    const float* W2  = (const float*)d_in[3];
    const float* b2  = (const float*)d_in[4];
    const float* Wf1 = (const float*)d_in[5];
    const float* bf1 = (const float*)d_in[6];
    const float* Wf2 = (const float*)d_in[7];
    const float* bf2 = (const float*)d_in[8];
    const int*   ei    = (const int*)d_in[9];
    const int*   batch = (const int*)d_in[10];
    const int* src = ei;        // edge_index row 0
    const int* dst = ei + NE;   // edge_index row 1
    float* out = (float*)d_out;

    const int BT  = 256;
    const int gbN = (NN + BT - 1) / BT;               // 586
    const int gbE = (NE + BT - 1) / BT;               // 18750
    const int NPB = BT / H;                           // 16 nodes per gather block
    const int gbG = (NN + NPB - 1) / NPB;             // 9375  (was 586 — the bug)
    const int gbP = (NG + NPB - 1) / NPB;             // 32

    // ---- workspace layout (4-byte units, 16B-aligned regions) ----
    // cnt[NN] | rs[NN+1] pad| cursor[NN] | bsum[1024] | bscan[1024] | csr[NE]
    // | disq[NN] | bufA[NN*H] | bufB[NN*H] | g[NG*H]
    size_t need = ((size_t)10210244) * 4;   // ~40.9 MB
    if (ws_size >= need) {
        int*   cnt    = (int*)d_ws;
        int*   rs     = cnt + NN;                 // NN+1 used, pad to 150004
        int*   cursor = cnt + 300004;
        int*   bsum   = cnt + 450004;
        int*   bscan  = cnt + 451028;
        int*   csr    = cnt + 452052;
        float* disq   = (float*)(cnt + 5252052);
        float* bufA   = (float*)(cnt + 5402052);
        float* bufB   = (float*)(cnt + 7802052);
        float* g      = (float*)(cnt + 10202052);

        // CSR build
        hipMemsetAsync(cnt, 0, (size_t)NN * sizeof(int), stream);
        k_count<<<gbE, BT, 0, stream>>>(dst, cnt);
        k_scan1<<<NB1, SCAN_BS, 0, stream>>>(cnt, rs, bsum);
        k_scan2<<<1, 1024, 0, stream>>>(bsum, bscan);
        k_scan3<<<gbN, BT, 0, stream>>>(cnt, bscan, rs, cursor, disq);
        k_place<<<gbE, BT, 0, stream>>>(src, dst, cursor, csr);

        // conv1
        k_xw1<<<gbN, BT, 0, stream>>>(x, W1, disq, bufA);
        k_gather<<<gbG, BT, 0, stream>>>(rs, csr, bufA, disq, b1, bufB);   // h1
        // conv2
        k_hw2<<<gbN, BT, 0, stream>>>(bufB, W2, disq, bufA);               // y2
        k_gather<<<gbG, BT, 0, stream>>>(rs, csr, bufA, disq, b2, bufB);   // h2
        // pool + MLP
        k_pool_seg<<<gbP, BT, 0, stream>>>(bufB, batch, g);
        k_mlp<<<1, 512, 0, stream>>>(g, Wf1, bf1, Wf2, bf2, out);
    } else {
        // fallback: baseline atomic-scatter path (~20 MB ws)
        float* disq = (float*)d_ws;
        float* bufA = disq + NN;
        float* bufB = bufA + (size_t)NN * H;
        float* g    = bufB + (size_t)NN * H;

        k_deg_init<<<gbN, BT, 0, stream>>>(disq);
        k_deg_edges<<<gbE, BT, 0, stream>>>(dst, disq);
        k_disq<<<gbN, BT, 0, stream>>>(disq);

        k_xw1<<<gbN, BT, 0, stream>>>(x, W1, disq, bufA);
        hipMemcpyAsync(bufB, bufA, (size_t)NN * H * sizeof(float),
                       hipMemcpyDeviceToDevice, stream);                   // acc = y (self)
        k_scatter<<<gbE, BT, 0, stream>>>(src, dst, bufA, bufB);
        k_post<<<gbN, BT, 0, stream>>>(bufB, disq, b1, bufA);              // h1

        k_hw2<<<gbN, BT, 0, stream>>>(bufA, W2, disq, bufB);               // y2
        hipMemcpyAsync(bufA, bufB, (size_t)NN * H * sizeof(float),
                       hipMemcpyDeviceToDevice, stream);
        k_scatter<<<gbE, BT, 0, stream>>>(src, dst, bufB, bufA);
        k_post<<<gbN, BT, 0, stream>>>(bufA, disq, b2, bufB);              // h2

        k_pool_seg<<<gbP, BT, 0, stream>>>(bufB, batch, g);
        k_mlp<<<1, 512, 0, stream>>>(g, Wf1, bf1, Wf2, bf2, out);
    }
}

// Round 7
// 836.883 us; speedup vs baseline: 10.0014x; 1.1041x over previous
//
#include <hip/hip_runtime.h>

constexpr int NN = 150000;   // nodes
constexpr int NE = 4800000;  // edges
constexpr int NG = 512;      // graphs
constexpr int H  = 16;       // hidden

// ============ linked-list build: nxt[i] = old head of dst[i] ============
// 1 atomic per edge; nxt write is coalesced (index i) -> no write amplification.
__global__ void k_build(const int* __restrict__ dst, int* __restrict__ head,
                        int* __restrict__ nxt) {
    int i = blockIdx.x * blockDim.x + threadIdx.x;
    if (i < NE) nxt[i] = atomicExch(&head[dst[i]], i);
}

// ============ fused: deg via chain walk -> disq; y = (x @ W1) * disq ============
// 1 thread per node: 64 independent chain walks per wave hide per-step latency.
__global__ void k_xw1deg(const float* __restrict__ x, const float* __restrict__ W1,
                         const int* __restrict__ head, const int* __restrict__ nxt,
                         float* __restrict__ disq, float* __restrict__ y) {
    __shared__ float w[4 * H];
    if (threadIdx.x < 4 * H) w[threadIdx.x] = W1[threadIdx.x];
    __syncthreads();
    int n = blockIdx.x * blockDim.x + threadIdx.x;
    if (n >= NN) return;
    int c = 1;                                   // self-loop
    for (int e = head[n]; e != -1; e = nxt[e]) ++c;
    float d = rsqrtf((float)c);
    disq[n] = d;
    float4 xv = ((const float4*)x)[n];
    float o[H];
#pragma unroll
    for (int h = 0; h < H; ++h)
        o[h] = (xv.x * w[0*H + h] + xv.y * w[1*H + h] +
                xv.z * w[2*H + h] + xv.w * w[3*H + h]) * d;
    float4* yp = (float4*)(y + (size_t)n * H);
#pragma unroll
    for (int q = 0; q < 4; ++q) yp[q] = ((float4*)o)[q];
}

// ============ gather via chain walk: h[n] = relu(disq[n]*(y[n]+sum y[src]) + b) ============
// 16 lanes per node: nxt[e]/src[e] are wave-broadcast 4B loads, y row is a 64B coalesced load.
__global__ void k_gather_ll(const int* __restrict__ head, const int* __restrict__ nxt,
                            const int* __restrict__ srcarr,
                            const float* __restrict__ y, const float* __restrict__ disq,
                            const float* __restrict__ b, float* __restrict__ hout) {
    int n    = blockIdx.x * (blockDim.x / H) + threadIdx.x / H;
    int lane = threadIdx.x & (H - 1);
    if (n >= NN) return;
    float acc = y[(size_t)n * H + lane];         // self-loop term
    for (int e = head[n]; e != -1; e = nxt[e])
        acc += y[(size_t)srcarr[e] * H + lane];
    hout[(size_t)n * H + lane] = fmaxf(fmaf(acc, disq[n], b[lane]), 0.f);
}

// ================= y = (h @ W2) * disq =================
__global__ void k_hw2(const float* __restrict__ hin, const float* __restrict__ W2,
                      const float* __restrict__ disq, float* __restrict__ yout) {
    __shared__ float w[H * H];
    if (threadIdx.x < H * H) w[threadIdx.x] = W2[threadIdx.x];
    __syncthreads();
    int i = blockIdx.x * blockDim.x + threadIdx.x;
    if (i >= NN) return;
    float hv[H];
    const float4* hp = (const float4*)(hin + (size_t)i * H);
#pragma unroll
    for (int q = 0; q < 4; ++q) ((float4*)hv)[q] = hp[q];
    float d = disq[i];
    float o[H];
#pragma unroll
    for (int h = 0; h < H; ++h) {
        float s = 0.f;
#pragma unroll
        for (int k = 0; k < H; ++k) s += hv[k] * w[k*H + h];
        o[h] = s * d;
    }
    float4* yp = (float4*)(yout + (size_t)i * H);
#pragma unroll
    for (int q = 0; q < 4; ++q) yp[q] = ((float4*)o)[q];
}

// ============ pool: batch sorted -> binary-search segmented sum ============
__global__ void k_pool_seg(const float* __restrict__ h, const int* __restrict__ batch,
                           float* __restrict__ gout) {
    int g    = blockIdx.x * (blockDim.x / H) + threadIdx.x / H;
    int lane = threadIdx.x & (H - 1);
    if (g >= NG) return;
    int lo = 0, hi = NN;
    while (lo < hi) { int m = (lo + hi) >> 1; if (batch[m] < g) lo = m + 1; else hi = m; }
    int start = lo;
    hi = NN;
    while (lo < hi) { int m = (lo + hi) >> 1; if (batch[m] < g + 1) lo = m + 1; else hi = m; }
    int end = lo;
    float acc = 0.f;
    for (int i = start; i < end; ++i) acc += h[(size_t)i * H + lane];
    gout[(size_t)g * H + lane] = acc;
}

// ================= final MLP =================
__global__ void k_mlp(const float* __restrict__ g, const float* __restrict__ Wf1,
                      const float* __restrict__ bf1, const float* __restrict__ Wf2,
                      const float* __restrict__ bf2, float* __restrict__ out) {
    __shared__ float w1[H * H];
    __shared__ float b1s[H];
    __shared__ float w2[H];
    __shared__ float b2s;
    if (threadIdx.x < H * H) w1[threadIdx.x] = Wf1[threadIdx.x];
    if (threadIdx.x < H) { b1s[threadIdx.x] = bf1[threadIdx.x]; w2[threadIdx.x] = Wf2[threadIdx.x]; }
    if (threadIdx.x == 0) b2s = bf2[0];
    __syncthreads();
    int i = blockIdx.x * blockDim.x + threadIdx.x;
    if (i >= NG) return;
    float gv[H];
    const float4* gp = (const float4*)(g + (size_t)i * H);
#pragma unroll
    for (int q = 0; q < 4; ++q) ((float4*)gv)[q] = gp[q];
    float s2 = 0.f;
#pragma unroll
    for (int h = 0; h < H; ++h) {
        float t = b1s[h];
#pragma unroll
        for (int k = 0; k < H; ++k) t += gv[k] * w1[k*H + h];
        s2 += fmaxf(t, 0.f) * w2[h];
    }
    out[i] = s2 + b2s;
}

// ================= fallback (baseline atomic path) =================
__global__ void k_xw1(const float* __restrict__ x, const float* __restrict__ W1,
                      const float* __restrict__ disq, float* __restrict__ y) {
    __shared__ float w[4 * H];
    if (threadIdx.x < 4 * H) w[threadIdx.x] = W1[threadIdx.x];
    __syncthreads();
    int i = blockIdx.x * blockDim.x + threadIdx.x;
    if (i >= NN) return;
    float4 xv = ((const float4*)x)[i];
    float d = disq[i];
    float o[H];
#pragma unroll
    for (int h = 0; h < H; ++h)
        o[h] = (xv.x * w[0*H + h] + xv.y * w[1*H + h] +
                xv.z * w[2*H + h] + xv.w * w[3*H + h]) * d;
    float4* yp = (float4*)(y + (size_t)i * H);
#pragma unroll
    for (int q = 0; q < 4; ++q) yp[q] = ((float4*)o)[q];
}
__global__ void k_deg_init(float* __restrict__ deg) {
    int i = blockIdx.x * blockDim.x + threadIdx.x;
    if (i < NN) deg[i] = 1.0f;
}
__global__ void k_deg_edges(const int* __restrict__ dst, float* __restrict__ deg) {
    int i = blockIdx.x * blockDim.x + threadIdx.x;
    if (i < NE) atomicAdd(&deg[dst[i]], 1.0f);
}
__global__ void k_disq(float* __restrict__ deg) {
    int i = blockIdx.x * blockDim.x + threadIdx.x;
    if (i < NN) deg[i] = rsqrtf(deg[i]);
}
__global__ void k_scatter(const int* __restrict__ src, const int* __restrict__ dst,
                          const float* __restrict__ y, float* __restrict__ acc) {
    int i = blockIdx.x * blockDim.x + threadIdx.x;
    if (i >= NE) return;
    int s = src[i], d = dst[i];
    const float4* yp = (const float4*)(y + (size_t)s * H);
    float* ap = acc + (size_t)d * H;
#pragma unroll
    for (int q = 0; q < 4; ++q) {
        float4 v = yp[q];
        atomicAdd(ap + q*4 + 0, v.x);
        atomicAdd(ap + q*4 + 1, v.y);
        atomicAdd(ap + q*4 + 2, v.z);
        atomicAdd(ap + q*4 + 3, v.w);
    }
}
__global__ void k_post(const float* __restrict__ acc, const float* __restrict__ disq,
                       const float* __restrict__ b, float* __restrict__ hout) {
    __shared__ float bs[H];
    if (threadIdx.x < H) bs[threadIdx.x] = b[threadIdx.x];
    __syncthreads();
    int i = blockIdx.x * blockDim.x + threadIdx.x;
    if (i >= NN) return;
    float d = disq[i];
    const float4* ap = (const float4*)(acc + (size_t)i * H);
    float4* hp = (float4*)(hout + (size_t)i * H);
#pragma unroll
    for (int q = 0; q < 4; ++q) {
        float4 v = ap[q];
        float4 r;
        r.x = fmaxf(v.x * d + bs[q*4+0], 0.f);
        r.y = fmaxf(v.y * d + bs[q*4+1], 0.f);
        r.z = fmaxf(v.z * d + bs[q*4+2], 0.f);
        r.w = fmaxf(v.w * d + bs[q*4+3], 0.f);
        hp[q] = r;
    }
}

extern "C" void kernel_launch(void* const* d_in, const int* in_sizes, int n_in,
                              void* d_out, int out_size, void* d_ws, size_t ws_size,
                              hipStream_t stream) {
    const float* x   = (const float*)d_in[0];
    const float* W1  = (const float*)d_in[1];
    const float* b1  = (const float*)d_in[2];
    const float* W2  = (const float*)d_in[3];
    const float* b2  = (const float*)d_in[4];
    const float* Wf1 = (const float*)d_in[5];
    const float* bf1 = (const float*)d_in[6];
    const float* Wf2 = (const float*)d_in[7];
    const float* bf2 = (const float*)d_in[8];
    const int*   ei    = (const int*)d_in[9];
    const int*   batch = (const int*)d_in[10];
    const int* src = ei;        // edge_index row 0
    const int* dst = ei + NE;   // edge_index row 1
    float* out = (float*)d_out;

    const int BT  = 256;
    const int gbN = (NN + BT - 1) / BT;               // 586
    const int gbE = (NE + BT - 1) / BT;               // 18750
    const int NPB = BT / H;                           // 16 nodes per gather block
    const int gbG = (NN + NPB - 1) / NPB;             // 9375
    const int gbP = (NG + NPB - 1) / NPB;             // 32

    // ---- workspace layout (4-byte units; every region start 16B-aligned) ----
    // head[NN] pad150016 | nxt[NE] | disq[NN] pad150000 | bufA[NN*H] | bufB[NN*H] | g[NG*H]
    size_t need = ((size_t)9908208) * 4;   // ~39.6 MB
    if (ws_size >= need) {
        int*   head = (int*)d_ws;
        int*   nxt  = head + 150016;
        float* disq = (float*)(head + 4950016);
        float* bufA = (float*)(head + 5100016);
        float* bufB = (float*)(head + 7500016);
        float* g    = (float*)(head + 9900016);

        // linked-list build (replaces memset+count+scan+place)
        hipMemsetAsync(head, 0xFF, (size_t)NN * sizeof(int), stream);   // head = -1
        k_build<<<gbE, BT, 0, stream>>>(dst, head, nxt);

        // conv1 (deg fused into xw1)
        k_xw1deg<<<gbN, BT, 0, stream>>>(x, W1, head, nxt, disq, bufA);
        k_gather_ll<<<gbG, BT, 0, stream>>>(head, nxt, src, bufA, disq, b1, bufB);  // h1
        // conv2
        k_hw2<<<gbN, BT, 0, stream>>>(bufB, W2, disq, bufA);                        // y2
        k_gather_ll<<<gbG, BT, 0, stream>>>(head, nxt, src, bufA, disq, b2, bufB);  // h2
        // pool + MLP
        k_pool_seg<<<gbP, BT, 0, stream>>>(bufB, batch, g);
        k_mlp<<<1, 512, 0, stream>>>(g, Wf1, bf1, Wf2, bf2, out);
    } else {
        // fallback: baseline atomic-scatter path (~20 MB ws)
        float* disq = (float*)d_ws;
        float* bufA = disq + NN;
        float* bufB = bufA + (size_t)NN * H;
        float* g    = bufB + (size_t)NN * H;

        k_deg_init<<<gbN, BT, 0, stream>>>(disq);
        k_deg_edges<<<gbE, BT, 0, stream>>>(dst, disq);
        k_disq<<<gbN, BT, 0, stream>>>(disq);

        k_xw1<<<gbN, BT, 0, stream>>>(x, W1, disq, bufA);
        hipMemcpyAsync(bufB, bufA, (size_t)NN * H * sizeof(float),
                       hipMemcpyDeviceToDevice, stream);
        k_scatter<<<gbE, BT, 0, stream>>>(src, dst, bufA, bufB);
        k_post<<<gbN, BT, 0, stream>>>(bufB, disq, b1, bufA);

        k_hw2<<<gbN, BT, 0, stream>>>(bufA, W2, disq, bufB);
        hipMemcpyAsync(bufA, bufB, (size_t)NN * H * sizeof(float),
                       hipMemcpyDeviceToDevice, stream);
        k_scatter<<<gbE, BT, 0, stream>>>(src, dst, bufB, bufA);
        k_post<<<gbN, BT, 0, stream>>>(bufA, disq, b2, bufB);

        k_pool_seg<<<gbP, BT, 0, stream>>>(bufB, batch, g);
        k_mlp<<<1, 512, 0, stream>>>(g, Wf1, bf1, Wf2, bf2, out);
    }
}